// Round 1
// 505.639 us; speedup vs baseline: 1.1348x; 1.1348x over previous
//
#include <hip/hip_runtime.h>
#include <hip/hip_bf16.h>
#include <stdint.h>

typedef __attribute__((ext_vector_type(8))) short short8;
typedef __attribute__((ext_vector_type(4))) float f32x4;
typedef __attribute__((ext_vector_type(8))) unsigned short ushort8v;

__device__ __forceinline__ unsigned short f2bf(float f) {
  union { float f; uint32_t u; } v; v.f = f;
  uint32_t u = v.u;
  u += 0x7fffu + ((u >> 16) & 1u);   // round-to-nearest-even
  return (unsigned short)(u >> 16);
}
__device__ __forceinline__ unsigned short f2h(float f) {
  union { _Float16 h; unsigned short u; } v; v.h = (_Float16)f; return v.u;
}
__device__ __forceinline__ float h2f(unsigned short u) {
  union { _Float16 h; unsigned short u; } v; v.u = u; return (float)v.h;
}

typedef const __attribute__((address_space(1))) unsigned int* gas_ptr;
typedef __attribute__((address_space(3))) unsigned int* las_ptr;

// DMA 16B per lane: LDS dst = wave-uniform base + lane*16 (hardware rule)
__device__ __forceinline__ void async16(const unsigned short* g, unsigned short* l) {
  __builtin_amdgcn_global_load_lds((gas_ptr)g, (las_ptr)l, 16, 0, 0);
}

#define FENCE() asm volatile("" ::: "memory")
#define BARRIER() do { FENCE(); __builtin_amdgcn_s_barrier(); FENCE(); } while (0)

// ---------------------------------------------------------------------------
// 256x256 8-phase GEMM:  C = A * B^T, all-bf16 inputs.  A:[M,K], B:[N,K].
// 512 threads = 8 waves (2M x 4N); per-wave C = 128x64 as acc[8][4] of
// 16x16x32 bf16 MFMA fragments.
// LDS = 2 buffers x {A,B} x 2 K-half regions; region = 256 rows x 32 cols
// bf16 (16 KB).  Total 128 KB.  Region staged by 2 global_load_lds issues;
// 16B chunk s of row r lives at slot s ^ ((r>>1)&3) (source pre-swizzled,
// LDS dest linear) -> every frag ds_read_b128 is 2-way on banks (free).
// Per K-tile: 4 phases {ds_read subtile; stage 1 half-region; barrier;
// setprio(1); 16 MFMA; setprio(0); barrier}.  Stages run 3 half-regions
// ahead into regions dead by phase-barrier proof; single counted
// s_waitcnt vmcnt(6) per K-tile (phase 4) -- loads survive barriers.
// EPI 0: bf16 = val + bias[col]; EPI 1: fp16 = val*scale; EPI 2: f32 = val*scale
// ---------------------------------------------------------------------------
#define BM 256
#define BN 256
#define BK 64
#define RGN 8192   // ushorts per region (256 rows x 32 cols)

template<int EPI>
__global__ __launch_bounds__(512, 2) void gemm256(
    const unsigned short* __restrict__ Abase,
    const unsigned short* __restrict__ Bbase,
    void* __restrict__ Cbase, const float* __restrict__ bias, float scale,
    int lda, int ldb, int ldc, int K, int mtiles, int ntiles,
    long long sA, long long sB, long long sC)
{
  __shared__ __align__(16) unsigned short lds[8 * RGN];   // 128 KB

  const int tid  = threadIdx.x;
  const int nwg  = (int)gridDim.x;
  const int flat = (int)blockIdx.x;
  // XCD-aware bijective swizzle (all launches have nwg % 8 == 0)
  const int swz = (flat & 7) * (nwg >> 3) + (flat >> 3);
  const int per = mtiles * ntiles;
  const int z   = swz / per;
  const int rm  = swz - z * per;
  const int mb  = rm / ntiles;
  const int nb  = rm - mb * ntiles;
  const int m0  = mb * BM;
  const int n0  = nb * BN;

  const int wave = tid >> 6;
  const int lane = tid & 63;
  const int l16  = lane & 15;
  const int quad = lane >> 4;
  const int wm   = wave >> 2;   // 0..1 -> row offset wm*128
  const int wn   = wave & 3;    // 0..3 -> col offset wn*64

  const unsigned short* A = Abase + (size_t)z * (size_t)sA;
  const unsigned short* B = Bbase + (size_t)z * (size_t)sB;

  // per-thread fragment read offsets (ushort units within a region)
  const int RA   = wm * 128 + l16;                    // + mt*16 -> row
  const int RB   = wn * 64  + l16;                    // + nt*16 -> row
  const int offA = RA * 32 + (quad ^ ((RA >> 1) & 3)) * 8;   // + mt*512
  const int offB = RB * 32 + (quad ^ ((RB >> 1) & 3)) * 8;   // + nt*512

  f32x4 acc[8][4] = {};

  const int nt = K / BK;

  // region index: buf*4 + ab*2 + h   (ab: 0=A, 1=B; h: K-half)
  auto stageA = [&](int kt, int h, int b) {
    unsigned short* rgn = lds + (size_t)(b * 4 + h) * RGN;
    #pragma unroll
    for (int i = 0; i < 2; ++i) {
      const int c  = i * 512 + tid;            // chunk index [0,1024)
      const int r  = c >> 2;                   // row
      const int s  = c & 3;                    // LDS slot in row
      const int sc = s ^ ((r >> 1) & 3);       // global chunk (pre-swizzle)
      async16(A + (size_t)(m0 + r) * lda + kt * 64 + h * 32 + sc * 8,
              rgn + (size_t)(i * 512 + wave * 64) * 8);
    }
  };
  auto stageB = [&](int kt, int h, int b) {
    unsigned short* rgn = lds + (size_t)(b * 4 + 2 + h) * RGN;
    #pragma unroll
    for (int i = 0; i < 2; ++i) {
      const int c  = i * 512 + tid;
      const int r  = c >> 2;
      const int s  = c & 3;
      const int sc = s ^ ((r >> 1) & 3);
      async16(B + (size_t)(n0 + r) * ldb + kt * 64 + h * 32 + sc * 8,
              rgn + (size_t)(i * 512 + wave * 64) * 8);
    }
  };

  // prologue: tile0 complete + tile1 {A-h0, B-h0, A-h1} (3 half-regions ahead)
  stageA(0, 0, 0); stageB(0, 0, 0); stageA(0, 1, 0); stageB(0, 1, 0);
  stageA(1, 0, 1); stageB(1, 0, 1); stageA(1, 1, 1);
  asm volatile("s_waitcnt vmcnt(6)" ::: "memory");   // tile0 landed
  BARRIER();

#define MFMA_QUAD(AF, BF, J0)                                                   \
  do {                                                                          \
    __builtin_amdgcn_s_setprio(1);                                              \
    _Pragma("unroll")                                                           \
    for (int mt = 0; mt < 8; ++mt) {                                            \
      acc[mt][J0]     = __builtin_amdgcn_mfma_f32_16x16x32_bf16(                \
          AF[mt], BF[J0],     acc[mt][J0],     0, 0, 0);                        \
      acc[mt][J0 + 1] = __builtin_amdgcn_mfma_f32_16x16x32_bf16(                \
          AF[mt], BF[J0 + 1], acc[mt][J0 + 1], 0, 0, 0);                        \
    }                                                                           \
    __builtin_amdgcn_s_setprio(0);                                              \
  } while (0)

  int cur = 0;
  for (int t = 0; t < nt; ++t, cur ^= 1) {
    const unsigned short* Ah0 = lds + (size_t)(cur * 4 + 0) * RGN;
    const unsigned short* Ah1 = Ah0 + RGN;
    const unsigned short* Bh0 = lds + (size_t)(cur * 4 + 2) * RGN;
    const unsigned short* Bh1 = Bh0 + RGN;

    short8 a0[8], a1[8], b0[4], b1[4];

    // ---- phase 1: read A[h0](8) + B[h0](4); stage B-h1(t+1); MFMA h0 x n0-1
    #pragma unroll
    for (int mt = 0; mt < 8; ++mt) a0[mt] = *(const short8*)&Ah0[offA + mt * 512];
    #pragma unroll
    for (int j = 0; j < 4; ++j)    b0[j]  = *(const short8*)&Bh0[offB + j * 512];
    if (t + 1 < nt) stageB(t + 1, 1, cur ^ 1);
    BARRIER();
    MFMA_QUAD(a0, b0, 0);
    BARRIER();

    // ---- phase 2: read A[h1](8); stage A-h0(t+2) over dead region; MFMA h0 x n2-3
    #pragma unroll
    for (int mt = 0; mt < 8; ++mt) a1[mt] = *(const short8*)&Ah1[offA + mt * 512];
    if (t + 2 < nt) stageA(t + 2, 0, cur);
    BARRIER();
    MFMA_QUAD(a0, b0, 2);
    BARRIER();

    // ---- phase 3: read B[h1](4); stage B-h0(t+2); MFMA h1 x n0-1
    #pragma unroll
    for (int j = 0; j < 4; ++j) b1[j] = *(const short8*)&Bh1[offB + j * 512];
    if (t + 2 < nt) stageB(t + 2, 0, cur);
    BARRIER();
    MFMA_QUAD(a1, b1, 0);
    BARRIER();

    // ---- phase 4: stage A-h1(t+2); counted vmcnt (tile t+1 fully landed); MFMA h1 x n2-3
    if (t + 2 < nt) stageA(t + 2, 1, cur);
    if (t < nt - 2)       asm volatile("s_waitcnt vmcnt(6)" ::: "memory");
    else if (t == nt - 2) asm volatile("s_waitcnt vmcnt(0)" ::: "memory");
    BARRIER();
    MFMA_QUAD(a1, b1, 2);
    BARRIER();
  }

  // ---- epilogue.  D layout: col = lane&15, row = quad*4 + reg ----
  #pragma unroll
  for (int mt = 0; mt < 8; ++mt) {
    const int Rg = m0 + wm * 128 + mt * 16 + quad * 4;
    #pragma unroll
    for (int j = 0; j < 4; ++j) {
      const int Cg = n0 + wn * 64 + j * 16 + l16;
      float badd = 0.f;
      if (EPI == 0) badd = bias[Cg];
      #pragma unroll
      for (int r = 0; r < 4; ++r) {
        const size_t off = (size_t)z * (size_t)sC + (size_t)(Rg + r) * ldc + Cg;
        const float val = acc[mt][j][r];
        if (EPI == 0) {
          ((unsigned short*)Cbase)[off] = f2bf(val + badd);
        } else if (EPI == 1) {
          ((unsigned short*)Cbase)[off] = f2h(val * scale);
        } else {
          ((float*)Cbase)[off] = val * scale;
        }
      }
    }
  }
}

// ---------------------------------------------------------------------------
// fp32 -> bf16 elementwise for the three [8,2048,1024] inputs (z selects).
// ---------------------------------------------------------------------------
__global__ __launch_bounds__(256) void cvt3_bf16(
    const float* __restrict__ a, const float* __restrict__ b,
    const float* __restrict__ c,
    unsigned short* __restrict__ oa, unsigned short* __restrict__ ob,
    unsigned short* __restrict__ oc)
{
  const float* src = blockIdx.z == 0 ? a : (blockIdx.z == 1 ? b : c);
  unsigned short* dst = blockIdx.z == 0 ? oa : (blockIdx.z == 1 ? ob : oc);
  const size_t base = ((size_t)blockIdx.x * 256 + threadIdx.x) * 8;
  const float4 t0 = *(const float4*)(src + base);
  const float4 t1 = *(const float4*)(src + base + 4);
  ushort8v h;
  h[0] = f2bf(t0.x); h[1] = f2bf(t0.y); h[2] = f2bf(t0.z); h[3] = f2bf(t0.w);
  h[4] = f2bf(t1.x); h[5] = f2bf(t1.y); h[6] = f2bf(t1.z); h[7] = f2bf(t1.w);
  *(ushort8v*)(dst + base) = h;
}

// ---------------------------------------------------------------------------
// Wq [1024x1024] fp32 -> Wt [1024x1024] bf16 transposed
// ---------------------------------------------------------------------------
__global__ __launch_bounds__(256) void transpose_w(
    const float* __restrict__ W, unsigned short* __restrict__ Wt)
{
  __shared__ float tile[64][65];
  const int k0 = blockIdx.x * 64;
  const int n0 = blockIdx.y * 64;
  #pragma unroll
  for (int i = 0; i < 16; ++i) {
    int lin = threadIdx.x + i * 256;
    int r = lin >> 6, c = lin & 63;
    tile[r][c] = W[(size_t)(k0 + r) * 1024 + n0 + c];
  }
  __syncthreads();
  #pragma unroll
  for (int i = 0; i < 16; ++i) {
    int lin = threadIdx.x + i * 256;
    int r = lin >> 6, c = lin & 63;
    Wt[(size_t)(n0 + r) * 1024 + k0 + c] = f2bf(tile[c][r]);
  }
}

// ---------------------------------------------------------------------------
// v [b][2048][1024] bf16 -> vT [b][1024][2048] bf16
// ---------------------------------------------------------------------------
__global__ __launch_bounds__(256) void transpose_v(
    const unsigned short* __restrict__ V, unsigned short* __restrict__ VT)
{
  __shared__ unsigned short tile[64][66];
  const int b  = blockIdx.z;
  const int s0 = blockIdx.x * 64;
  const int d0 = blockIdx.y * 64;
  const unsigned short* Vb  = V  + (size_t)b * 2048 * 1024;
  unsigned short*       VTb = VT + (size_t)b * 1024 * 2048;
  #pragma unroll
  for (int i = 0; i < 16; ++i) {
    int lin = threadIdx.x + i * 256;
    int r = lin >> 6, c = lin & 63;
    tile[r][c] = Vb[(size_t)(s0 + r) * 1024 + d0 + c];
  }
  __syncthreads();
  #pragma unroll
  for (int i = 0; i < 16; ++i) {
    int lin = threadIdx.x + i * 256;
    int r = lin >> 6, c = lin & 63;
    VTb[(size_t)(d0 + r) * 2048 + s0 + c] = tile[c][r];
  }
}

// ---------------------------------------------------------------------------
// Row softmax: read fp16 logits row (2048), write bf16 P row (2048).
// ---------------------------------------------------------------------------
__global__ __launch_bounds__(256) void softmax_rows(
    const unsigned short* __restrict__ Lh, unsigned short* __restrict__ P)
{
  const int row  = blockIdx.x;
  const unsigned short* pin = Lh + (size_t)row * 2048;
  unsigned short*       pout = P + (size_t)row * 2048;
  const int tid  = threadIdx.x;
  const int lane = tid & 63;
  const int wave = tid >> 6;

  const ushort8v h = ((const ushort8v*)pin)[tid];
  float x[8];
  #pragma unroll
  for (int e = 0; e < 8; ++e) x[e] = h2f(h[e]);

  float mx = x[0];
  #pragma unroll
  for (int e = 1; e < 8; ++e) mx = fmaxf(mx, x[e]);
  #pragma unroll
  for (int o = 32; o > 0; o >>= 1) mx = fmaxf(mx, __shfl_xor(mx, o));
  __shared__ float redm[4];
  if (lane == 0) redm[wave] = mx;
  __syncthreads();
  mx = fmaxf(fmaxf(redm[0], redm[1]), fmaxf(redm[2], redm[3]));

  float s = 0.f;
  #pragma unroll
  for (int e = 0; e < 8; ++e) { x[e] = __expf(x[e] - mx); s += x[e]; }
  #pragma unroll
  for (int o = 32; o > 0; o >>= 1) s += __shfl_xor(s, o);
  __shared__ float reds[4];
  if (lane == 0) reds[wave] = s;
  __syncthreads();
  s = reds[0] + reds[1] + reds[2] + reds[3];

  const float inv = 1.0f / s;
  ushort8v o8;
  #pragma unroll
  for (int e = 0; e < 8; ++e) o8[e] = f2bf(x[e] * inv);
  ((ushort8v*)pout)[tid] = o8;
}

// ---------------------------------------------------------------------------
extern "C" void kernel_launch(void* const* d_in, const int* in_sizes, int n_in,
                              void* d_out, int out_size, void* d_ws, size_t ws_size,
                              hipStream_t stream)
{
  const float* query = (const float*)d_in[0];
  const float* key   = (const float*)d_in[1];
  const float* value = (const float*)d_in[2];
  const float* Wq    = (const float*)d_in[3];
  const float* bq    = (const float*)d_in[4];
  float* out = (float*)d_out;

  // workspace (MB offsets), peak 226 MB:
  //   Wt  [0,2)     bf16 W^T
  //   Xq  [2,34) Xk [34,66) Xv [66,98)    bf16 inputs (contiguous -> one GEMM)
  //   q   [98,130) k [130,162) v [162,194) bf16 projections (contiguous)
  //   vT  [2,34)    over dead Xq
  //   lgH [34,98)   fp16 logits over dead Xk/Xv
  //   P   [98,162)  bf16 probs over dead q/k
  char* ws = (char*)d_ws;
  unsigned short* Wt  = (unsigned short*)(ws);
  unsigned short* Xq  = (unsigned short*)(ws + ((size_t)2   << 20));
  unsigned short* Xk  = (unsigned short*)(ws + ((size_t)34  << 20));
  unsigned short* Xv  = (unsigned short*)(ws + ((size_t)66  << 20));
  unsigned short* q   = (unsigned short*)(ws + ((size_t)98  << 20));
  unsigned short* v   = (unsigned short*)(ws + ((size_t)162 << 20));
  unsigned short* vT  = (unsigned short*)(ws + ((size_t)2   << 20));
  unsigned short* lgH = (unsigned short*)(ws + ((size_t)34  << 20));
  unsigned short* P   = (unsigned short*)(ws + ((size_t)98  << 20));

  // 1. W transpose->bf16 ; inputs fp32->bf16
  transpose_w<<<dim3(16, 16, 1), 256, 0, stream>>>(Wq, Wt);
  cvt3_bf16<<<dim3(8192, 1, 3), 256, 0, stream>>>(query, key, value, Xq, Xk, Xv);

  // 2. projections (single dispatch over contiguous X/q-k-v):
  //    bf16 = X @ Wt^T + bq   (M=16384, N=1024, K=1024, z=3) -> 64x4x3 = 768 wg
  gemm256<0><<<dim3(768, 1, 1), 512, 0, stream>>>(
      Xq, Wt, q, bq, 1.0f, 1024, 1024, 1024, 1024, 64, 4,
      (long long)16384 * 1024, 0, (long long)16384 * 1024);

  // 3. v -> vT  (writes over dead Xq)
  transpose_v<<<dim3(32, 16, 8), 256, 0, stream>>>(v, vT);

  // 4. logits[fp16] = (q @ k^T)/32  per batch (M=N=2048, K=1024) -> 8x8x8 = 512 wg
  gemm256<1><<<dim3(512, 1, 1), 512, 0, stream>>>(
      q, q + (size_t)32 * 1024 * 1024 / 2, lgH, nullptr, 0.03125f,
      1024, 1024, 2048, 1024, 8, 8,
      (long long)2048 * 1024, (long long)2048 * 1024, (long long)2048 * 2048);

  // 5. softmax rows -> bf16 P (writes over dead q/k)
  softmax_rows<<<dim3(8 * 2048, 1, 1), 256, 0, stream>>>(lgH, P);

  // 6. out[f32] = P @ vT^T  per batch (M=2048, N=1024, K=2048) -> 8x4x8 = 256 wg
  gemm256<2><<<dim3(256, 1, 1), 512, 0, stream>>>(
      P, vT, out, nullptr, 1.0f, 2048, 2048, 1024, 2048, 8, 4,
      (long long)2048 * 2048, (long long)1024 * 2048, (long long)2048 * 1024);
}

// Round 2
// 491.392 us; speedup vs baseline: 1.1677x; 1.0290x over previous
//
#include <hip/hip_runtime.h>
#include <hip/hip_bf16.h>
#include <stdint.h>

typedef __attribute__((ext_vector_type(8))) short short8;
typedef __attribute__((ext_vector_type(4))) float f32x4;
typedef __attribute__((ext_vector_type(8))) unsigned short ushort8v;

__device__ __forceinline__ unsigned short f2bf(float f) {
  union { float f; uint32_t u; } v; v.f = f;
  uint32_t u = v.u;
  u += 0x7fffu + ((u >> 16) & 1u);   // round-to-nearest-even
  return (unsigned short)(u >> 16);
}
__device__ __forceinline__ unsigned short f2h(float f) {
  union { _Float16 h; unsigned short u; } v; v.h = (_Float16)f; return v.u;
}
__device__ __forceinline__ float h2f(unsigned short u) {
  union { _Float16 h; unsigned short u; } v; v.u = u; return (float)v.h;
}

typedef const __attribute__((address_space(1))) unsigned int* gas_ptr;
typedef __attribute__((address_space(3))) unsigned int* las_ptr;

// DMA 16B per lane: LDS dst = wave-uniform base + lane*16 (hardware rule)
__device__ __forceinline__ void async16(const unsigned short* g, unsigned short* l) {
  __builtin_amdgcn_global_load_lds((gas_ptr)g, (las_ptr)l, 16, 0, 0);
}

#define FENCE() asm volatile("" ::: "memory")
#define BARRIER() do { FENCE(); __builtin_amdgcn_s_barrier(); FENCE(); } while (0)

// ---------------------------------------------------------------------------
// 256x256 pipelined 4-phase GEMM:  C = A * B^T, all-bf16.  A:[M,K], B:[N,K].
// 512 threads = 8 waves (2M x 4N); per-wave C = 128x64 as acc[8][4] of
// 16x16x32 bf16 MFMA fragments.
// LDS = 2 buffers x {A,B} x 2 K-half regions; region = 256 rows x 32 cols
// bf16 (16 KB), total 128 KB.  16B chunk s of row r at slot s ^ ((r>>1)&3)
// (source pre-swizzled, LDS dest linear) -> frag ds_read_b128 2-way (free).
//
// Fragment ds_reads are pipelined ONE PHASE AHEAD of their consuming MFMA,
// so every lgkmcnt wait targets reads issued >=1 phase (>=512 cyc of MFMA
// backlog) earlier -- LDS service overlaps the matrix pipe instead of
// preceding it.  Per K-tile: 4 phases, 4 barriers, ONE counted vmcnt(6)
// (never 0 until the tail):
//   ph1: MFMA(a0,b0,n0-1) | read a1      | stage B-h1(t+1) | bar
//   ph2: MFMA(a0,b0,n2-3) | read b1      | stage A-h0(t+2) | bar
//   ph3: MFMA(a1,b1,n0-1) |              | stage B-h0(t+2) | bar
//   ph4: stage A-h1(t+2); vmcnt(6); bar; MFMA(a1,b1,n2-3) | read a0,b0(t+1)
// Hazard proof: each region's last ds_read completes (forced by register
// use at an MFMA issue) before the barrier preceding its overwriting DMA;
// each read is covered by the prior tile's vmcnt(6)+barrier (vmcnt is
// per-wave; the barrier makes region-complete a block-wide fact).
// EPI 0: bf16 = val + bias[col]; EPI 1: fp16 = val*scale; EPI 2: f32 = val*scale
// ---------------------------------------------------------------------------
#define BM 256
#define BN 256
#define BK 64
#define RGN 8192   // ushorts per region (256 rows x 32 cols)

template<int EPI>
__global__ __launch_bounds__(512, 2) void gemm256(
    const unsigned short* __restrict__ Abase,
    const unsigned short* __restrict__ Bbase,
    void* __restrict__ Cbase, const float* __restrict__ bias, float scale,
    int lda, int ldb, int ldc, int K, int mtiles, int ntiles,
    long long sA, long long sB, long long sC)
{
  __shared__ __align__(16) unsigned short lds[8 * RGN];   // 128 KB

  const int tid  = threadIdx.x;
  const int nwg  = (int)gridDim.x;
  const int flat = (int)blockIdx.x;
  // XCD-aware bijective swizzle (all launches have nwg % 8 == 0)
  const int swz = (flat & 7) * (nwg >> 3) + (flat >> 3);
  const int per = mtiles * ntiles;
  const int z   = swz / per;
  const int rm  = swz - z * per;
  const int mb  = rm / ntiles;
  const int nb  = rm - mb * ntiles;
  const int m0  = mb * BM;
  const int n0  = nb * BN;

  const int wave = tid >> 6;
  const int lane = tid & 63;
  const int l16  = lane & 15;
  const int quad = lane >> 4;
  const int wm   = wave >> 2;   // 0..1 -> row offset wm*128
  const int wn   = wave & 3;    // 0..3 -> col offset wn*64

  const unsigned short* A = Abase + (size_t)z * (size_t)sA;
  const unsigned short* B = Bbase + (size_t)z * (size_t)sB;

  // per-thread fragment read offsets (ushort units within a region)
  const int RA   = wm * 128 + l16;                    // + mt*16 -> row
  const int RB   = wn * 64  + l16;                    // + nt*16 -> row
  const int offA = RA * 32 + (quad ^ ((RA >> 1) & 3)) * 8;   // + mt*512
  const int offB = RB * 32 + (quad ^ ((RB >> 1) & 3)) * 8;   // + nt*512

  f32x4 acc[8][4] = {};

  const int nt = K / BK;

  // region index: buf*4 + ab*2 + h   (ab: 0=A, 1=B; h: K-half)
  auto stageA = [&](int kt, int h, int b) {
    unsigned short* rgn = lds + (size_t)(b * 4 + h) * RGN;
    #pragma unroll
    for (int i = 0; i < 2; ++i) {
      const int c  = i * 512 + tid;            // chunk index [0,1024)
      const int r  = c >> 2;                   // row
      const int s  = c & 3;                    // LDS slot in row
      const int sc = s ^ ((r >> 1) & 3);       // global chunk (pre-swizzle)
      async16(A + (size_t)(m0 + r) * lda + kt * 64 + h * 32 + sc * 8,
              rgn + (size_t)(i * 512 + wave * 64) * 8);
    }
  };
  auto stageB = [&](int kt, int h, int b) {
    unsigned short* rgn = lds + (size_t)(b * 4 + 2 + h) * RGN;
    #pragma unroll
    for (int i = 0; i < 2; ++i) {
      const int c  = i * 512 + tid;
      const int r  = c >> 2;
      const int s  = c & 3;
      const int sc = s ^ ((r >> 1) & 3);
      async16(B + (size_t)(n0 + r) * ldb + kt * 64 + h * 32 + sc * 8,
              rgn + (size_t)(i * 512 + wave * 64) * 8);
    }
  };

  // prologue: tile0 complete + tile1 {A-h0, B-h0, A-h1} (3 half-regions ahead)
  stageA(0, 0, 0); stageB(0, 0, 0); stageA(0, 1, 0); stageB(0, 1, 0);
  stageA(1, 0, 1); stageB(1, 0, 1); stageA(1, 1, 1);
  asm volatile("s_waitcnt vmcnt(6)" ::: "memory");   // tile0 landed
  BARRIER();

#define MFMA_QUAD(AF, BF, J0)                                                   \
  do {                                                                          \
    __builtin_amdgcn_s_setprio(1);                                              \
    _Pragma("unroll")                                                           \
    for (int mt = 0; mt < 8; ++mt) {                                            \
      acc[mt][J0]     = __builtin_amdgcn_mfma_f32_16x16x32_bf16(                \
          AF[mt], BF[J0],     acc[mt][J0],     0, 0, 0);                        \
      acc[mt][J0 + 1] = __builtin_amdgcn_mfma_f32_16x16x32_bf16(                \
          AF[mt], BF[J0 + 1], acc[mt][J0 + 1], 0, 0, 0);                        \
    }                                                                           \
    __builtin_amdgcn_s_setprio(0);                                              \
  } while (0)

  short8 a0[8], a1[8], b0[4], b1[4];
  // pre-read tile-0 h0 fragments (one-time lgkm exposure)
  {
    const unsigned short* Ah0 = lds;
    const unsigned short* Bh0 = lds + (size_t)2 * RGN;
    #pragma unroll
    for (int mt = 0; mt < 8; ++mt) a0[mt] = *(const short8*)&Ah0[offA + mt * 512];
    #pragma unroll
    for (int j = 0; j < 4; ++j)    b0[j]  = *(const short8*)&Bh0[offB + j * 512];
  }

  int cur = 0;
  for (int t = 0; t < nt; ++t, cur ^= 1) {
    const unsigned short* Ah1 = lds + (size_t)(cur * 4 + 1) * RGN;
    const unsigned short* Bh1 = lds + (size_t)(cur * 4 + 3) * RGN;

    // ---- phase 1: MFMA h0 x n0-1; read a1 (this tile); stage B-h1(t+1)
    MFMA_QUAD(a0, b0, 0);
    #pragma unroll
    for (int mt = 0; mt < 8; ++mt) a1[mt] = *(const short8*)&Ah1[offA + mt * 512];
    if (t + 1 < nt) stageB(t + 1, 1, cur ^ 1);
    BARRIER();

    // ---- phase 2: MFMA h0 x n2-3; read b1 (this tile); stage A-h0(t+2)
    MFMA_QUAD(a0, b0, 2);
    #pragma unroll
    for (int j = 0; j < 4; ++j) b1[j] = *(const short8*)&Bh1[offB + j * 512];
    if (t + 2 < nt) stageA(t + 2, 0, cur);
    BARRIER();

    // ---- phase 3: MFMA h1 x n0-1; stage B-h0(t+2)
    MFMA_QUAD(a1, b1, 0);
    if (t + 2 < nt) stageB(t + 2, 0, cur);
    BARRIER();

    // ---- phase 4: stage A-h1(t+2); counted vmcnt (tile t+1 fully landed);
    //      barrier; MFMA h1 x n2-3; read next tile's a0,b0
    if (t + 2 < nt) stageA(t + 2, 1, cur);
    if (t < nt - 2)       asm volatile("s_waitcnt vmcnt(6)" ::: "memory");
    else if (t == nt - 2) asm volatile("s_waitcnt vmcnt(0)" ::: "memory");
    BARRIER();
    MFMA_QUAD(a1, b1, 2);
    if (t + 1 < nt) {
      const unsigned short* nAh0 = lds + (size_t)((cur ^ 1) * 4 + 0) * RGN;
      const unsigned short* nBh0 = lds + (size_t)((cur ^ 1) * 4 + 2) * RGN;
      #pragma unroll
      for (int mt = 0; mt < 8; ++mt) a0[mt] = *(const short8*)&nAh0[offA + mt * 512];
      #pragma unroll
      for (int j = 0; j < 4; ++j)    b0[j]  = *(const short8*)&nBh0[offB + j * 512];
    }
    // no end-of-tile barrier needed: next overwrite of any region this
    // tile read is >= 2 barriers away (see hazard proof in header comment)
  }

  // ---- epilogue.  D layout: col = lane&15, row = quad*4 + reg ----
  #pragma unroll
  for (int mt = 0; mt < 8; ++mt) {
    const int Rg = m0 + wm * 128 + mt * 16 + quad * 4;
    #pragma unroll
    for (int j = 0; j < 4; ++j) {
      const int Cg = n0 + wn * 64 + j * 16 + l16;
      float badd = 0.f;
      if (EPI == 0) badd = bias[Cg];
      #pragma unroll
      for (int r = 0; r < 4; ++r) {
        const size_t off = (size_t)z * (size_t)sC + (size_t)(Rg + r) * ldc + Cg;
        const float val = acc[mt][j][r];
        if (EPI == 0) {
          ((unsigned short*)Cbase)[off] = f2bf(val + badd);
        } else if (EPI == 1) {
          ((unsigned short*)Cbase)[off] = f2h(val * scale);
        } else {
          ((float*)Cbase)[off] = val * scale;
        }
      }
    }
  }
}

// ---------------------------------------------------------------------------
// fp32 -> bf16 elementwise for the three [8,2048,1024] inputs (z selects).
// ---------------------------------------------------------------------------
__global__ __launch_bounds__(256) void cvt3_bf16(
    const float* __restrict__ a, const float* __restrict__ b,
    const float* __restrict__ c,
    unsigned short* __restrict__ oa, unsigned short* __restrict__ ob,
    unsigned short* __restrict__ oc)
{
  const float* src = blockIdx.z == 0 ? a : (blockIdx.z == 1 ? b : c);
  unsigned short* dst = blockIdx.z == 0 ? oa : (blockIdx.z == 1 ? ob : oc);
  const size_t base = ((size_t)blockIdx.x * 256 + threadIdx.x) * 8;
  const float4 t0 = *(const float4*)(src + base);
  const float4 t1 = *(const float4*)(src + base + 4);
  ushort8v h;
  h[0] = f2bf(t0.x); h[1] = f2bf(t0.y); h[2] = f2bf(t0.z); h[3] = f2bf(t0.w);
  h[4] = f2bf(t1.x); h[5] = f2bf(t1.y); h[6] = f2bf(t1.z); h[7] = f2bf(t1.w);
  *(ushort8v*)(dst + base) = h;
}

// ---------------------------------------------------------------------------
// Wq [1024x1024] fp32 -> Wt [1024x1024] bf16 transposed
// ---------------------------------------------------------------------------
__global__ __launch_bounds__(256) void transpose_w(
    const float* __restrict__ W, unsigned short* __restrict__ Wt)
{
  __shared__ float tile[64][65];
  const int k0 = blockIdx.x * 64;
  const int n0 = blockIdx.y * 64;
  #pragma unroll
  for (int i = 0; i < 16; ++i) {
    int lin = threadIdx.x + i * 256;
    int r = lin >> 6, c = lin & 63;
    tile[r][c] = W[(size_t)(k0 + r) * 1024 + n0 + c];
  }
  __syncthreads();
  #pragma unroll
  for (int i = 0; i < 16; ++i) {
    int lin = threadIdx.x + i * 256;
    int r = lin >> 6, c = lin & 63;
    Wt[(size_t)(n0 + r) * 1024 + k0 + c] = f2bf(tile[c][r]);
  }
}

// ---------------------------------------------------------------------------
// v [b][2048][1024] bf16 -> vT [b][1024][2048] bf16
// ---------------------------------------------------------------------------
__global__ __launch_bounds__(256) void transpose_v(
    const unsigned short* __restrict__ V, unsigned short* __restrict__ VT)
{
  __shared__ unsigned short tile[64][66];
  const int b  = blockIdx.z;
  const int s0 = blockIdx.x * 64;
  const int d0 = blockIdx.y * 64;
  const unsigned short* Vb  = V  + (size_t)b * 2048 * 1024;
  unsigned short*       VTb = VT + (size_t)b * 1024 * 2048;
  #pragma unroll
  for (int i = 0; i < 16; ++i) {
    int lin = threadIdx.x + i * 256;
    int r = lin >> 6, c = lin & 63;
    tile[r][c] = Vb[(size_t)(s0 + r) * 1024 + d0 + c];
  }
  __syncthreads();
  #pragma unroll
  for (int i = 0; i < 16; ++i) {
    int lin = threadIdx.x + i * 256;
    int r = lin >> 6, c = lin & 63;
    VTb[(size_t)(d0 + r) * 2048 + s0 + c] = tile[c][r];
  }
}

// ---------------------------------------------------------------------------
// Row softmax: read fp16 logits row (2048), write bf16 P row (2048).
// ---------------------------------------------------------------------------
__global__ __launch_bounds__(256) void softmax_rows(
    const unsigned short* __restrict__ Lh, unsigned short* __restrict__ P)
{
  const int row  = blockIdx.x;
  const unsigned short* pin = Lh + (size_t)row * 2048;
  unsigned short*       pout = P + (size_t)row * 2048;
  const int tid  = threadIdx.x;
  const int lane = tid & 63;
  const int wave = tid >> 6;

  const ushort8v h = ((const ushort8v*)pin)[tid];
  float x[8];
  #pragma unroll
  for (int e = 0; e < 8; ++e) x[e] = h2f(h[e]);

  float mx = x[0];
  #pragma unroll
  for (int e = 1; e < 8; ++e) mx = fmaxf(mx, x[e]);
  #pragma unroll
  for (int o = 32; o > 0; o >>= 1) mx = fmaxf(mx, __shfl_xor(mx, o));
  __shared__ float redm[4];
  if (lane == 0) redm[wave] = mx;
  __syncthreads();
  mx = fmaxf(fmaxf(redm[0], redm[1]), fmaxf(redm[2], redm[3]));

  float s = 0.f;
  #pragma unroll
  for (int e = 0; e < 8; ++e) { x[e] = __expf(x[e] - mx); s += x[e]; }
  #pragma unroll
  for (int o = 32; o > 0; o >>= 1) s += __shfl_xor(s, o);
  __shared__ float reds[4];
  if (lane == 0) reds[wave] = s;
  __syncthreads();
  s = reds[0] + reds[1] + reds[2] + reds[3];

  const float inv = 1.0f / s;
  ushort8v o8;
  #pragma unroll
  for (int e = 0; e < 8; ++e) o8[e] = f2bf(x[e] * inv);
  ((ushort8v*)pout)[tid] = o8;
}

// ---------------------------------------------------------------------------
extern "C" void kernel_launch(void* const* d_in, const int* in_sizes, int n_in,
                              void* d_out, int out_size, void* d_ws, size_t ws_size,
                              hipStream_t stream)
{
  const float* query = (const float*)d_in[0];
  const float* key   = (const float*)d_in[1];
  const float* value = (const float*)d_in[2];
  const float* Wq    = (const float*)d_in[3];
  const float* bq    = (const float*)d_in[4];
  float* out = (float*)d_out;

  // workspace (MB offsets), peak 226 MB:
  //   Wt  [0,2)     bf16 W^T
  //   Xq  [2,34) Xk [34,66) Xv [66,98)    bf16 inputs (contiguous -> one GEMM)
  //   q   [98,130) k [130,162) v [162,194) bf16 projections (contiguous)
  //   vT  [2,34)    over dead Xq
  //   lgH [34,98)   fp16 logits over dead Xk/Xv
  //   P   [98,162)  bf16 probs over dead q/k
  char* ws = (char*)d_ws;
  unsigned short* Wt  = (unsigned short*)(ws);
  unsigned short* Xq  = (unsigned short*)(ws + ((size_t)2   << 20));
  unsigned short* Xk  = (unsigned short*)(ws + ((size_t)34  << 20));
  unsigned short* Xv  = (unsigned short*)(ws + ((size_t)66  << 20));
  unsigned short* q   = (unsigned short*)(ws + ((size_t)98  << 20));
  unsigned short* v   = (unsigned short*)(ws + ((size_t)162 << 20));
  unsigned short* vT  = (unsigned short*)(ws + ((size_t)2   << 20));
  unsigned short* lgH = (unsigned short*)(ws + ((size_t)34  << 20));
  unsigned short* P   = (unsigned short*)(ws + ((size_t)98  << 20));

  // 1. W transpose->bf16 ; inputs fp32->bf16
  transpose_w<<<dim3(16, 16, 1), 256, 0, stream>>>(Wq, Wt);
  cvt3_bf16<<<dim3(8192, 1, 3), 256, 0, stream>>>(query, key, value, Xq, Xk, Xv);

  // 2. projections (single dispatch over contiguous X/q-k-v):
  //    bf16 = X @ Wt^T + bq   (M=16384, N=1024, K=1024, z=3) -> 64x4x3 = 768 wg
  gemm256<0><<<dim3(768, 1, 1), 512, 0, stream>>>(
      Xq, Wt, q, bq, 1.0f, 1024, 1024, 1024, 1024, 64, 4,
      (long long)16384 * 1024, 0, (long long)16384 * 1024);

  // 3. v -> vT  (writes over dead Xq)
  transpose_v<<<dim3(32, 16, 8), 256, 0, stream>>>(v, vT);

  // 4. logits[fp16] = (q @ k^T)/32  per batch (M=N=2048, K=1024) -> 8x8x8 = 512 wg
  gemm256<1><<<dim3(512, 1, 1), 512, 0, stream>>>(
      q, q + (size_t)32 * 1024 * 1024 / 2, lgH, nullptr, 0.03125f,
      1024, 1024, 2048, 1024, 8, 8,
      (long long)2048 * 1024, (long long)2048 * 1024, (long long)2048 * 2048);

  // 5. softmax rows -> bf16 P (writes over dead q/k)
  softmax_rows<<<dim3(8 * 2048, 1, 1), 256, 0, stream>>>(lgH, P);

  // 6. out[f32] = P @ vT^T  per batch (M=2048, N=1024, K=2048) -> 8x4x8 = 256 wg
  gemm256<2><<<dim3(256, 1, 1), 512, 0, stream>>>(
      P, vT, out, nullptr, 1.0f, 2048, 2048, 1024, 2048, 8, 4,
      (long long)2048 * 2048, (long long)1024 * 2048, (long long)2048 * 1024);
}